// Round 1
// baseline (2707.206 us; speedup 1.0000x reference)
//
#include <hip/hip_runtime.h>
#include <hip/hip_fp16.h>

// Many2OneRNN: B=64, S=4096, I=256, H=256, O=128
// Phase 1 (k_xp):  xp[b,t,h] = sum_i x[b,t,i]*Wax_w[h,i] + Wax_b[h]   (MFMA f16)
// Phase 2 (k_rnn): a = tanh(xp_t + Waa*a + Waa_b), 1 block per batch chain,
//                  weights in registers, v_dot2_f32_f16, 1 raw barrier/step.
// Phase 3: folded into last k_rnn launch: out = sigmoid(Wya*a + Wya_b).

typedef _Float16 f16x8 __attribute__((ext_vector_type(8)));
typedef _Float16 f16x2 __attribute__((ext_vector_type(2)));
typedef float    f32x4 __attribute__((ext_vector_type(4)));

#if __has_builtin(__builtin_amdgcn_fdot2)
#define FDOT2(a, b, c) __builtin_amdgcn_fdot2((a), (b), (c), false)
#else
#define FDOT2(a, b, c) ((c) + (float)(a)[0] * (float)(b)[0] + (float)(a)[1] * (float)(b)[1])
#endif

// ---------------------------------------------------------------------------
// Phase 1: xp GEMM.  grid = (64*T_C)/32 blocks, 512 threads.
// Block computes 32 rows x 256 cols.  8 waves: wave wv owns cols wv*32..+32.
// Weights (B operand) live in registers; A tile staged f32->f16 in LDS.
// ---------------------------------------------------------------------------
__global__ __launch_bounds__(512) void k_xp(
    const float* __restrict__ x, const float* __restrict__ Ww,
    const float* __restrict__ Wb, float* __restrict__ xp,
    int c, int T_C, int logT)
{
    __shared__ __align__(16) _Float16 As[32 * 264];  // pad 256->264 halves
    const int tid  = threadIdx.x;
    const int lane = tid & 63;
    const int wv   = tid >> 6;   // 0..7
    const int l15  = lane & 15;
    const int lk   = lane >> 4;  // 0..3
    const int n0   = wv * 32;

    // --- B fragments (Wax_w rows = N dim, K contiguous) in registers
    f16x8 bfr[2][8];
#pragma unroll
    for (int nt = 0; nt < 2; ++nt) {
        const float* wrow = Ww + (size_t)(n0 + nt * 16 + l15) * 256;
#pragma unroll
        for (int kt = 0; kt < 8; ++kt) {
            const float4* wp = (const float4*)(wrow + kt * 32 + lk * 8);
            float4 v0 = wp[0], v1 = wp[1];
            f16x8 f;
            f[0] = (_Float16)v0.x; f[1] = (_Float16)v0.y;
            f[2] = (_Float16)v0.z; f[3] = (_Float16)v0.w;
            f[4] = (_Float16)v1.x; f[5] = (_Float16)v1.y;
            f[6] = (_Float16)v1.z; f[7] = (_Float16)v1.w;
            bfr[nt][kt] = f;
        }
    }
    const float bias0 = Wb[n0 + l15];
    const float bias1 = Wb[n0 + 16 + l15];

    // --- stage A tile (32 rows x 256 K) f32 -> f16 LDS
    {
        const int arow = tid >> 4;
        const int acol = (tid & 15) * 16;
        const int r    = blockIdx.x * 32 + arow;   // row within chunk
        const int b    = r >> logT;
        const int tl   = r & (T_C - 1);
        const float4* s4 = (const float4*)(x + ((size_t)(b * 4096 + c * T_C + tl) << 8) + acol);
        float4 v0 = s4[0], v1 = s4[1], v2 = s4[2], v3 = s4[3];
        f16x8 p0, p1;
        p0[0] = (_Float16)v0.x; p0[1] = (_Float16)v0.y;
        p0[2] = (_Float16)v0.z; p0[3] = (_Float16)v0.w;
        p0[4] = (_Float16)v1.x; p0[5] = (_Float16)v1.y;
        p0[6] = (_Float16)v1.z; p0[7] = (_Float16)v1.w;
        p1[0] = (_Float16)v2.x; p1[1] = (_Float16)v2.y;
        p1[2] = (_Float16)v2.z; p1[3] = (_Float16)v2.w;
        p1[4] = (_Float16)v3.x; p1[5] = (_Float16)v3.y;
        p1[6] = (_Float16)v3.z; p1[7] = (_Float16)v3.w;
        _Float16* d = As + arow * 264 + acol;
        *(f16x8*)(d)     = p0;
        *(f16x8*)(d + 8) = p1;
    }
    __syncthreads();

    f32x4 acc[2][2] = {};
#pragma unroll
    for (int kt = 0; kt < 8; ++kt) {
        f16x8 a0 = *(const f16x8*)(As + (l15)      * 264 + kt * 32 + lk * 8);
        f16x8 a1 = *(const f16x8*)(As + (16 + l15) * 264 + kt * 32 + lk * 8);
        acc[0][0] = __builtin_amdgcn_mfma_f32_16x16x32_f16(a0, bfr[0][kt], acc[0][0], 0, 0, 0);
        acc[0][1] = __builtin_amdgcn_mfma_f32_16x16x32_f16(a0, bfr[1][kt], acc[0][1], 0, 0, 0);
        acc[1][0] = __builtin_amdgcn_mfma_f32_16x16x32_f16(a1, bfr[0][kt], acc[1][0], 0, 0, 0);
        acc[1][1] = __builtin_amdgcn_mfma_f32_16x16x32_f16(a1, bfr[1][kt], acc[1][1], 0, 0, 0);
    }

    // --- store xp (f32), coalesced 64B per 16-lane group
    const size_t base = (size_t)blockIdx.x * 32;
#pragma unroll
    for (int mt = 0; mt < 2; ++mt) {
#pragma unroll
        for (int nt = 0; nt < 2; ++nt) {
            const int   colg = n0 + nt * 16 + l15;
            const float bias = (nt == 0) ? bias0 : bias1;
#pragma unroll
            for (int r2 = 0; r2 < 4; ++r2) {
                size_t row = base + mt * 16 + lk * 4 + r2;
                xp[(row << 8) + colg] = acc[mt][nt][r2] + bias;
            }
        }
    }
}

// ---------------------------------------------------------------------------
// Phase 2: recurrence.  grid = 64 blocks (1 per batch chain), 1024 threads.
// Thread (w, lane): h = w*16 + (lane&15), kq = lane>>4 owns K-quarter kq*64.
// Waa[h][kq*64..+64] as 32 f16x2 registers.  a double-buffered in LDS with
// [4][72]-half layout (kq chunks bank-disjoint).  xp register-prefetched.
// ---------------------------------------------------------------------------
__global__ __launch_bounds__(1024) void k_rnn(
    const float* __restrict__ xp, const float* __restrict__ Waa,
    const float* __restrict__ Wab, const float* __restrict__ Wya,
    const float* __restrict__ Wyb, float* __restrict__ out,
    unsigned short* __restrict__ a_state,
    int c, int T_C, int is_last)
{
    __shared__ __align__(16) _Float16 aL[2][4][72];  // [buf][kq-chunk][64+8 pad]
    __shared__ float afin[256];
    const int tid  = threadIdx.x;
    const int lane = tid & 63;
    const int w    = tid >> 6;    // 0..15
    const int l15  = lane & 15;
    const int kq   = lane >> 4;   // 0..3
    const int h    = w * 16 + l15;
    const int b    = blockIdx.x;

    // --- recurrent weights in registers (f16x2 pairs, K-contiguous)
    f16x2 wr[32];
    {
        const float4* wp = (const float4*)(Waa + (size_t)h * 256 + kq * 64);
#pragma unroll
        for (int i = 0; i < 16; ++i) {
            float4 v = wp[i];
            f16x2 t0; t0[0] = (_Float16)v.x; t0[1] = (_Float16)v.y;
            f16x2 t1; t1[0] = (_Float16)v.z; t1[1] = (_Float16)v.w;
            wr[2 * i]     = t0;
            wr[2 * i + 1] = t1;
        }
    }
    const float bias = Wab[h];

    // --- init a buffer 0 (chunk 0 => zeros, else carried f16 state)
    if (tid < 256) {
        unsigned short v = 0;
        if (c != 0) v = a_state[b * 256 + tid];
        aL[0][tid >> 6][tid & 63] = __builtin_bit_cast(_Float16, v);
    }
    __syncthreads();

    // --- xp register prefetch pipeline, depth 8
    const float* xpb = xp + (((size_t)b * T_C) << 8) + h;
    float xr[8];
#pragma unroll
    for (int j = 0; j < 8; ++j) xr[j] = xpb[(size_t)j << 8];

    const int cw = h >> 6;   // write chunk
    const int co = h & 63;

    for (int tb = 0; tb < T_C; tb += 8) {
#pragma unroll
        for (int j = 0; j < 8; ++j) {
            const int cur = j & 1, nxt = cur ^ 1;   // tb even -> parity static
            uint4 av[8];
            const uint4* ap = (const uint4*)(&aL[cur][kq][0]);
#pragma unroll
            for (int i = 0; i < 8; ++i) av[i] = ap[i];
            float s0 = 0.f, s1 = 0.f, s2 = 0.f, s3 = 0.f;
#pragma unroll
            for (int i = 0; i < 8; ++i) {
                s0 = FDOT2(wr[4 * i + 0], __builtin_bit_cast(f16x2, av[i].x), s0);
                s1 = FDOT2(wr[4 * i + 1], __builtin_bit_cast(f16x2, av[i].y), s1);
                s2 = FDOT2(wr[4 * i + 2], __builtin_bit_cast(f16x2, av[i].z), s2);
                s3 = FDOT2(wr[4 * i + 3], __builtin_bit_cast(f16x2, av[i].w), s3);
            }
            float p = (s0 + s1) + (s2 + s3);
            p += __shfl_xor(p, 16);
            p += __shfl_xor(p, 32);
            float z = p + bias + xr[j];
            if (tb + j + 8 < T_C) xr[j] = xpb[((size_t)(tb + j + 8)) << 8];
            float e  = __expf(-2.f * fabsf(z));
            float th = (1.f - e) * __builtin_amdgcn_rcpf(1.f + e);
            float a  = copysignf(th, z);
            if (kq == 0) {
                _Float16 ah = (_Float16)a;
                aL[nxt][cw][co] = ah;
                if (tb + j == T_C - 1) {
                    afin[h] = a;
                    a_state[b * 256 + h] = __builtin_bit_cast(unsigned short, ah);
                }
            }
            // raw barrier: wait LDS only -- must NOT drain vmcnt (xp prefetch
            // stays in flight across steps).  Empty asm = compiler fence so
            // next step's LDS reads can't hoist above the barrier.
            asm volatile("s_waitcnt lgkmcnt(0)" ::: "memory");
            __builtin_amdgcn_s_barrier();
            asm volatile("" ::: "memory");
        }
    }

    // --- Phase 3: out = sigmoid(Wya * a_last + Wyb), last chunk only
    if (is_last) {
        const int o  = tid >> 3;   // 0..127
        const int k8 = tid & 7;    // 8-way K split within wave
        const float4* wp = (const float4*)(Wya + (size_t)o * 256 + k8 * 32);
        const float4* ap = (const float4*)(afin + k8 * 32);
        float s = 0.f;
#pragma unroll
        for (int i = 0; i < 8; ++i) {
            float4 wv4 = wp[i];
            float4 a4  = ap[i];
            s += wv4.x * a4.x + wv4.y * a4.y + wv4.z * a4.z + wv4.w * a4.w;
        }
        s += __shfl_xor(s, 1);
        s += __shfl_xor(s, 2);
        s += __shfl_xor(s, 4);
        if (k8 == 0)
            out[b * 128 + o] = __builtin_amdgcn_rcpf(1.f + __expf(-(s + Wyb[o])));
    }
}

// ---------------------------------------------------------------------------
extern "C" void kernel_launch(void* const* d_in, const int* in_sizes, int n_in,
                              void* d_out, int out_size, void* d_ws, size_t ws_size,
                              hipStream_t stream)
{
    (void)in_sizes; (void)n_in; (void)out_size;
    const float* x    = (const float*)d_in[0];
    const float* Waxw = (const float*)d_in[1];
    const float* Waxb = (const float*)d_in[2];
    const float* Waaw = (const float*)d_in[3];
    const float* Waab = (const float*)d_in[4];
    const float* Wyaw = (const float*)d_in[5];
    const float* Wyab = (const float*)d_in[6];
    float* out = (float*)d_out;

    // Adaptive chunking over timesteps so the f32 xp chunk fits in d_ws.
    int T_C = 4096, logT = 12;
    while (T_C > 32 && (size_t)64 * T_C * 256 * 4 + 32768 > ws_size) { T_C >>= 1; --logT; }

    float* xp = (float*)d_ws;
    unsigned short* a_state =
        (unsigned short*)((char*)d_ws + (size_t)64 * T_C * 256 * 4);

    const int nc = 4096 / T_C;
    for (int ci = 0; ci < nc; ++ci) {
        k_xp<<<dim3(2 * T_C), dim3(512), 0, stream>>>(x, Waxw, Waxb, xp, ci, T_C, logT);
        k_rnn<<<dim3(64), dim3(1024), 0, stream>>>(xp, Waaw, Waab, Wyaw, Wyab,
                                                   out, a_state, ci, T_C, ci == nc - 1);
    }
}